// Round 4
// baseline (165.974 us; speedup 1.0000x reference)
//
#include <hip/hip_runtime.h>

// NaiveFourierKANLayer: y = cos-features @ W0^T + sin-features @ W1^T + bias
// N=32768, INPUTDIM=64, OUTDIM=256, GRIDSIZE=32 -> GEMM M=32768, N=256, K=4096
//
// R6 changes vs R5 (86.5 us gemm, MfmaUtil 31.5, VALUBusy 23, conflicts 2.1M):
//  - MFMA shape 16x16x32 -> 32x32x16: measured pipe ceiling 2075 -> 2382+ TF
//    (+15%), MFMA instr count per wave-kt halved (32 -> 16), ds_read count
//    unchanged (12 b128; reuse is set by the 64x128 wave tile, not the shape).
//    MFMA floor 33 -> 28.8 us.
//  - A/B fragment addressing re-derived: row = lane&31, 8 contiguous k at
//    chunk (2*ks + (lane>>5)) -- same "8-contiguous-k per lane" pattern as
//    the harness-verified 16x16x32 usage.
//  - Epilogue uses the verified 32x32 C/D map: col=lane&31,
//    row=(reg&3)+8*(reg>>2)+4*(lane>>5)  [learn_hip m74/m101].
//  - Everything else (staging, XOR swizzle, 2-phase pipeline, split-k LDS
//    reduction, feature recurrence) byte-identical to R5.

#define IDIM 64
#define ODIM 256
#define KDIM 4096
#define BM 128

typedef __attribute__((ext_vector_type(8))) unsigned short ushort8_t;
typedef __bf16 bf16x8 __attribute__((ext_vector_type(8)));
typedef float floatx16 __attribute__((ext_vector_type(16)));

__device__ __forceinline__ unsigned short f2bf_rne(float f) {
  unsigned int u = __float_as_uint(f);
  return (unsigned short)((u + 0x7FFFu + ((u >> 16) & 1u)) >> 16);
}

__device__ __forceinline__ void gl_lds16(const void* g, void* l) {
  __builtin_amdgcn_global_load_lds(
      (__attribute__((address_space(1))) void*)g,
      (__attribute__((address_space(3))) void*)l, 16, 0, 0);
}

// ---- weight gather+convert: fc(2,256,64,32) fp32 -> Wr(256,4096) bf16 ----
__global__ void __launch_bounds__(256) wconv(const float* __restrict__ fc,
                                             unsigned short* __restrict__ Wr) {
  int e = (blockIdx.x * 256 + threadIdx.x) << 2;  // element idx, 4 per thread
  int o = e >> 12;
  int k = e & 4095;
  int i = k >> 6;
  int c = (k >> 5) & 1;
  int g = k & 31;  // multiple of 4
  const float4 v = *(const float4*)(fc + ((size_t)c << 19) + o * 2048 + i * 32 + g);
  ushort4 r;
  r.x = f2bf_rne(v.x);
  r.y = f2bf_rne(v.y);
  r.z = f2bf_rne(v.z);
  r.w = f2bf_rne(v.w);
  *(ushort4*)(Wr + e) = r;
}

// ---- fused feature-gen + GEMM ----
__global__ void __launch_bounds__(512, 2) fkan_gemm(const float* __restrict__ X,
                                                    const unsigned short* __restrict__ Wr,
                                                    const float* __restrict__ bias,
                                                    float* __restrict__ out) {
  // carved shared: As 2x16KB | Bs 2x32KB  (epilogue reuses front 66.5KB as f32 scratch)
  __shared__ __align__(16) unsigned char smem[98304];
  unsigned short* const AsBase = (unsigned short*)smem;            // 2 x 8192 ushorts
  unsigned short* const BsBase = (unsigned short*)(smem + 32768);  // 2 x 16384 ushorts

  const int t = threadIdx.x;
  const int wv = t >> 6;          // wave 0..7
  const int ln = t & 63;
  const int l31 = ln & 31;
  const int khi = ln >> 5;        // k-half within a 16-k MFMA window
  const int wk = wv & 1;          // k-half of the 64-k tile (chunks wk*4..wk*4+3)
  const int wn2 = (wv >> 1) & 1;  // col-half (128 cols)
  const int wm2 = wv >> 2;        // row-half (64 rows)
  const int m0 = blockIdx.x * BM;

  // feature role: 4 threads per row, thread q owns g = 8q+1 .. 8q+8
  const int arow = t >> 2;  // 0..127
  const int q = t & 3;
  const float g0f = (float)(8 * q + 1);

  // B-staging: swizzled source so LDS region granule l holds
  // (row = l>>3, chunk = (l&7)^(l>>3)); region = wv*4+j covers 8 rows
  const int brow_off = ln >> 3;
  const int bchunk = (ln & 7) ^ (ln >> 3);
  const unsigned short* bsrc[4];
#pragma unroll
  for (int j = 0; j < 4; ++j)
    bsrc[j] = Wr + (size_t)(wv * 32 + j * 8 + brow_off) * KDIM + bchunk * 8;

  // A write granules (kt-invariant, XOR-swizzled) — verified R2/R3 formulas
  const int ga_c = arow * 8 + (q ^ (arow & 7));
  const int ga_s = arow * 8 + ((4 + q) ^ (arow & 7));

  floatx16 acc[2][4];
#pragma unroll
  for (int a = 0; a < 2; ++a)
#pragma unroll
    for (int b = 0; b < 4; ++b)
#pragma unroll
      for (int e = 0; e < 16; ++e) acc[a][b][e] = 0.0f;

  const float* xptr = X + (size_t)(m0 + arow) * IDIM;

  // ---- B staging: async global->LDS, 4 regions (1KB) per wave, 32KB total
  auto stageB = [&](int ktn, int buf) {
#pragma unroll
    for (int j = 0; j < 4; ++j)
      gl_lds16(bsrc[j] + ktn * 64, BsBase + buf * 16384 + (wv * 4 + j) * 512);
  };

  // ---- A staging: chain-of-8 Fourier recurrence, one (cos,sin) granule pair
  auto features = [&](float xv, int buf) {
    const float inv2pi = 0.15915494309189535f;
    float u = xv * inv2pi;  // x in revolutions
    float u0 = u * g0f;     // g0*x in revolutions
    float c1 = __builtin_amdgcn_cosf(u);
    float s1 = __builtin_amdgcn_sinf(u);
    float C = __builtin_amdgcn_cosf(u0);
    float S = __builtin_amdgcn_sinf(u0);
    bf16x8 cb, sb;
    cb[0] = (__bf16)C;
    sb[0] = (__bf16)S;
#pragma unroll
    for (int j = 1; j < 8; ++j) {
      float Cn = __builtin_fmaf(C, c1, -(S * s1));
      float Sn = __builtin_fmaf(S, c1, (C * s1));
      C = Cn;
      S = Sn;
      cb[j] = (__bf16)C;
      sb[j] = (__bf16)S;
    }
    ushort8_t* As8 = (ushort8_t*)(AsBase + buf * 8192);
    As8[ga_c] = __builtin_bit_cast(ushort8_t, cb);
    As8[ga_s] = __builtin_bit_cast(ushort8_t, sb);
  };

  // ---- MFMA on buffer `buf`: one k-half per wave, 12 b128 reads, 16 MFMAs
  auto domfma = [&](int buf) {
    const ushort8_t* A8 = (const ushort8_t*)(AsBase + buf * 8192);
    const ushort8_t* B8 = (const ushort8_t*)(BsBase + buf * 16384);
    bf16x8 af[2][2], bfr[2][4];
#pragma unroll
    for (int ks = 0; ks < 2; ++ks) {
      const int ch = wk * 4 + ks * 2 + khi;  // chunk of 8 k-values this lane supplies
#pragma unroll
      for (int mt = 0; mt < 2; ++mt) {
        int r = wm2 * 64 + mt * 32 + l31;
        af[ks][mt] = __builtin_bit_cast(bf16x8, A8[r * 8 + (ch ^ (r & 7))]);
      }
#pragma unroll
      for (int nt = 0; nt < 4; ++nt) {
        int n = wn2 * 128 + nt * 32 + l31;
        bfr[ks][nt] = __builtin_bit_cast(bf16x8, B8[n * 8 + (ch ^ (n & 7))]);
      }
    }
#pragma unroll
    for (int ks = 0; ks < 2; ++ks)
#pragma unroll
      for (int mt = 0; mt < 2; ++mt)
#pragma unroll
        for (int nt = 0; nt < 4; ++nt)
          acc[mt][nt] = __builtin_amdgcn_mfma_f32_32x32x16_bf16(
              af[ks][mt], bfr[ks][nt], acc[mt][nt], 0, 0, 0);
  };

  // ---- prologue: fill buffer 0 with k-tile 0
  stageB(0, 0);
  features(xptr[0], 0);
  __syncthreads();

  // ---- steady state: unrolled x2 so dbuf index is compile-time
  for (int kt = 0; kt < 62; kt += 2) {
    {
      float xn = xptr[kt + 1];
      stageB(kt + 1, 1);  // loads in flight across MFMA+feature phase
      domfma(0);
      features(xn, 1);
      __syncthreads();
    }
    {
      float xn = xptr[kt + 2];
      stageB(kt + 2, 0);
      domfma(1);
      features(xn, 0);
      __syncthreads();
    }
  }
  {  // kt = 62
    float xn = xptr[63];
    stageB(63, 1);
    domfma(0);
    features(xn, 1);
    __syncthreads();
  }
  domfma(1);  // kt = 63, no prefetch

  // ---- split-k reduction + store, 32x32 C/D map:
  //      col = lane&31, row = (reg&3) + 8*(reg>>2) + 4*(lane>>5)
  float* red = (float*)smem;  // [64][260] f32 = 66560 B
  for (int half = 0; half < 2; ++half) {
    __syncthreads();  // all waves done with As/Bs (or previous round)
    if (wk == 1 && wm2 == half) {
#pragma unroll
      for (int mt = 0; mt < 2; ++mt)
#pragma unroll
        for (int nt = 0; nt < 4; ++nt) {
          int col = wn2 * 128 + nt * 32 + l31;
#pragma unroll
          for (int reg = 0; reg < 16; ++reg) {
            int row = mt * 32 + (reg & 3) + 8 * (reg >> 2) + 4 * khi;
            red[row * 260 + col] = acc[mt][nt][reg];
          }
        }
    }
    __syncthreads();
    if (wk == 0 && wm2 == half) {
#pragma unroll
      for (int nt = 0; nt < 4; ++nt) {
        int col = wn2 * 128 + nt * 32 + l31;
        float bv = bias[col];
#pragma unroll
        for (int mt = 0; mt < 2; ++mt)
#pragma unroll
          for (int reg = 0; reg < 16; ++reg) {
            int row = mt * 32 + (reg & 3) + 8 * (reg >> 2) + 4 * khi;
            out[(size_t)(m0 + half * 64 + row) * ODIM + col] =
                acc[mt][nt][reg] + red[row * 260 + col] + bv;
          }
      }
    }
  }
}

extern "C" void kernel_launch(void* const* d_in, const int* in_sizes, int n_in,
                              void* d_out, int out_size, void* d_ws, size_t ws_size,
                              hipStream_t stream) {
  const float* x = (const float*)d_in[0];
  const float* fc = (const float*)d_in[1];
  const float* bias = (const float*)d_in[2];
  float* out = (float*)d_out;
  unsigned short* Wr = (unsigned short*)d_ws;  // 2 MB of workspace

  hipLaunchKernelGGL(wconv, dim3(1024), dim3(256), 0, stream, fc, Wr);
  hipLaunchKernelGGL(fkan_gemm, dim3(256), dim3(512), 0, stream, x, Wr, bias, out);
}

// Round 6
// 140.644 us; speedup vs baseline: 1.1801x; 1.1801x over previous
//
#include <hip/hip_runtime.h>

// NaiveFourierKANLayer: y = cos-features @ W0^T + sin-features @ W1^T + bias
// N=32768, INPUTDIM=64, OUTDIM=256, GRIDSIZE=32 -> GEMM M=32768, N=256, K=4096
//
// R8 == R7 resubmitted verbatim (R5 86.5us + interleaved k-step + setprio).
// R7's bench failed with "MI355X container failed twice" — an infra error,
// not a kernel verdict (no compile error, no pass/fail, no counters). The
// kernel has no new hang risk vs the verified R5: uniform barriers, static
// loop bounds; s_setprio is a pure scheduling hint.
//
// R7 changes vs R5 (86.5 us gemm, MfmaUtil 31.5, VALUBusy 23, conflicts 2.1M):
//  - k-step restructured: reads(af+bfr0-3) -> MFMA(nt0-3) -> features ->
//    reads(bfr4-7) -> MFMA(nt4-7) -> barrier. The features chain (independent
//    VALU/trans) now issues under MFMA half 1 (separate pipes) and under
//    half 2's ds_read latency; wave pairs per SIMD de-phase instead of
//    hitting the LDS port and MFMA pipe in lockstep.
//  - T5: s_setprio(1) around each MFMA cluster (role diversity now exists).
//  - Liveness kept <= R5 (bfr halves of 4; af carried across features).
//    Everything else (staging, XOR swizzle maps, split-k, epilogue) identical.

#define IDIM 64
#define ODIM 256
#define KDIM 4096
#define BM 128

typedef __attribute__((ext_vector_type(8))) unsigned short ushort8_t;
typedef __bf16 bf16x8 __attribute__((ext_vector_type(8)));
typedef float floatx4 __attribute__((ext_vector_type(4)));

__device__ __forceinline__ unsigned short f2bf_rne(float f) {
  unsigned int u = __float_as_uint(f);
  return (unsigned short)((u + 0x7FFFu + ((u >> 16) & 1u)) >> 16);
}

__device__ __forceinline__ void gl_lds16(const void* g, void* l) {
  __builtin_amdgcn_global_load_lds(
      (__attribute__((address_space(1))) void*)g,
      (__attribute__((address_space(3))) void*)l, 16, 0, 0);
}

// ---- weight gather+convert: fc(2,256,64,32) fp32 -> Wr(256,4096) bf16 ----
__global__ void __launch_bounds__(256) wconv(const float* __restrict__ fc,
                                             unsigned short* __restrict__ Wr) {
  int e = (blockIdx.x * 256 + threadIdx.x) << 2;  // element idx, 4 per thread
  int o = e >> 12;
  int k = e & 4095;
  int i = k >> 6;
  int c = (k >> 5) & 1;
  int g = k & 31;  // multiple of 4
  const float4 v = *(const float4*)(fc + ((size_t)c << 19) + o * 2048 + i * 32 + g);
  ushort4 r;
  r.x = f2bf_rne(v.x);
  r.y = f2bf_rne(v.y);
  r.z = f2bf_rne(v.z);
  r.w = f2bf_rne(v.w);
  *(ushort4*)(Wr + e) = r;
}

// ---- fused feature-gen + GEMM ----
__global__ void __launch_bounds__(512, 2) fkan_gemm(const float* __restrict__ X,
                                                    const unsigned short* __restrict__ Wr,
                                                    const float* __restrict__ bias,
                                                    float* __restrict__ out) {
  // carved shared: As 2x16KB | Bs 2x32KB  (epilogue reuses front 66.5KB as f32 scratch)
  __shared__ __align__(16) unsigned char smem[98304];
  unsigned short* const AsBase = (unsigned short*)smem;            // 2 x 8192 ushorts
  unsigned short* const BsBase = (unsigned short*)(smem + 32768);  // 2 x 16384 ushorts

  const int t = threadIdx.x;
  const int wv = t >> 6;          // wave 0..7
  const int ln = t & 63;
  const int lm = ln & 15;
  const int quad = ln >> 4;
  const int wk = wv & 1;          // k-half (chunks wk*4 .. wk*4+3)
  const int wn2 = (wv >> 1) & 1;  // col-half (128 cols)
  const int wm2 = wv >> 2;        // row-half (64 rows)
  const int m0 = blockIdx.x * BM;

  // feature role: 4 threads per row, thread q owns g = 8q+1 .. 8q+8
  const int arow = t >> 2;  // 0..127
  const int q = t & 3;
  const float g0f = (float)(8 * q + 1);

  // B-staging: swizzled source so LDS region granule l holds
  // (row = l>>3, chunk = (l&7)^(l>>3)); region = wv*4+j covers 8 rows
  const int brow_off = ln >> 3;
  const int bchunk = (ln & 7) ^ (ln >> 3);
  const unsigned short* bsrc[4];
#pragma unroll
  for (int j = 0; j < 4; ++j)
    bsrc[j] = Wr + (size_t)(wv * 32 + j * 8 + brow_off) * KDIM + bchunk * 8;

  // A write granules (kt-invariant, XOR-swizzled) — verified R2/R3 formulas
  const int ga_c = arow * 8 + (q ^ (arow & 7));
  const int ga_s = arow * 8 + ((4 + q) ^ (arow & 7));

  floatx4 acc[4][8];
#pragma unroll
  for (int a = 0; a < 4; ++a)
#pragma unroll
    for (int b = 0; b < 8; ++b)
      acc[a][b] = (floatx4){0.0f, 0.0f, 0.0f, 0.0f};

  const float* xptr = X + (size_t)(m0 + arow) * IDIM;

  // ---- B staging: async global->LDS, 4 regions (1KB) per wave, 32KB total
  auto stageB = [&](int ktn, int buf) {
#pragma unroll
    for (int j = 0; j < 4; ++j)
      gl_lds16(bsrc[j] + ktn * 64, BsBase + buf * 16384 + (wv * 4 + j) * 512);
  };

  // ---- A staging: chain-of-8 Fourier recurrence, one (cos,sin) granule pair
  auto features = [&](float xv, int buf) {
    const float inv2pi = 0.15915494309189535f;
    float u = xv * inv2pi;  // x in revolutions
    float u0 = u * g0f;     // g0*x in revolutions
    float c1 = __builtin_amdgcn_cosf(u);
    float s1 = __builtin_amdgcn_sinf(u);
    float C = __builtin_amdgcn_cosf(u0);
    float S = __builtin_amdgcn_sinf(u0);
    bf16x8 cb, sb;
    cb[0] = (__bf16)C;
    sb[0] = (__bf16)S;
#pragma unroll
    for (int j = 1; j < 8; ++j) {
      float Cn = __builtin_fmaf(C, c1, -(S * s1));
      float Sn = __builtin_fmaf(S, c1, (C * s1));
      C = Cn;
      S = Sn;
      cb[j] = (__bf16)C;
      sb[j] = (__bf16)S;
    }
    ushort8_t* As8 = (ushort8_t*)(AsBase + buf * 8192);
    As8[ga_c] = __builtin_bit_cast(ushort8_t, cb);
    As8[ga_s] = __builtin_bit_cast(ushort8_t, sb);
  };

  // ---- interleaved k-step: stage(nxt) | reads half1 | MFMA half1 |
  //      features(nxt) | reads half2 | MFMA half2 | barrier
  auto ktstep = [&](int ktn, int cur, int nxt) {
    float xn = xptr[ktn];
    stageB(ktn, nxt);

    const ushort8_t* A8 = (const ushort8_t*)(AsBase + cur * 8192);
    const ushort8_t* B8 = (const ushort8_t*)(BsBase + cur * 16384);
    const int ch = wk * 4 + quad;

    bf16x8 af[4], b0[4];
#pragma unroll
    for (int mt = 0; mt < 4; ++mt) {
      int r = wm2 * 64 + mt * 16 + lm;
      af[mt] = __builtin_bit_cast(bf16x8, A8[r * 8 + (ch ^ (r & 7))]);
    }
#pragma unroll
    for (int nt = 0; nt < 4; ++nt) {
      int n = wn2 * 128 + nt * 16 + lm;
      b0[nt] = __builtin_bit_cast(bf16x8, B8[n * 8 + (ch ^ (n & 7))]);
    }

    __builtin_amdgcn_s_setprio(1);
#pragma unroll
    for (int mt = 0; mt < 4; ++mt)
#pragma unroll
      for (int nt = 0; nt < 4; ++nt)
        acc[mt][nt] = __builtin_amdgcn_mfma_f32_16x16x32_bf16(
            af[mt], b0[nt], acc[mt][nt], 0, 0, 0);
    __builtin_amdgcn_s_setprio(0);

    features(xn, nxt);  // independent VALU/trans: overlaps MFMA1 + reads2

    bf16x8 b1[4];
#pragma unroll
    for (int nt = 0; nt < 4; ++nt) {
      int n = wn2 * 128 + (nt + 4) * 16 + lm;
      b1[nt] = __builtin_bit_cast(bf16x8, B8[n * 8 + (ch ^ (n & 7))]);
    }

    __builtin_amdgcn_s_setprio(1);
#pragma unroll
    for (int mt = 0; mt < 4; ++mt)
#pragma unroll
      for (int nt = 0; nt < 4; ++nt)
        acc[mt][nt + 4] = __builtin_amdgcn_mfma_f32_16x16x32_bf16(
            af[mt], b1[nt], acc[mt][nt + 4], 0, 0, 0);
    __builtin_amdgcn_s_setprio(0);

    __syncthreads();
  };

  // ---- tail MFMA (no stage/features), both halves
  auto domfma = [&](int buf) {
    const ushort8_t* A8 = (const ushort8_t*)(AsBase + buf * 8192);
    const ushort8_t* B8 = (const ushort8_t*)(BsBase + buf * 16384);
    const int ch = wk * 4 + quad;
    bf16x8 af[4], bfr[8];
#pragma unroll
    for (int mt = 0; mt < 4; ++mt) {
      int r = wm2 * 64 + mt * 16 + lm;
      af[mt] = __builtin_bit_cast(bf16x8, A8[r * 8 + (ch ^ (r & 7))]);
    }
#pragma unroll
    for (int nt = 0; nt < 8; ++nt) {
      int n = wn2 * 128 + nt * 16 + lm;
      bfr[nt] = __builtin_bit_cast(bf16x8, B8[n * 8 + (ch ^ (n & 7))]);
    }
#pragma unroll
    for (int mt = 0; mt < 4; ++mt)
#pragma unroll
      for (int nt = 0; nt < 8; ++nt)
        acc[mt][nt] = __builtin_amdgcn_mfma_f32_16x16x32_bf16(
            af[mt], bfr[nt], acc[mt][nt], 0, 0, 0);
  };

  // ---- prologue: fill buffer 0 with k-tile 0
  stageB(0, 0);
  features(xptr[0], 0);
  __syncthreads();

  // ---- steady state: unrolled x2 so dbuf index is compile-time
  for (int kt = 0; kt < 62; kt += 2) {
    ktstep(kt + 1, 0, 1);
    ktstep(kt + 2, 1, 0);
  }
  ktstep(63, 0, 1);
  domfma(1);  // kt = 63, no prefetch

  // ---- split-k reduction + store: wk=1 partials via padded LDS scratch ----
  float* red = (float*)smem;  // [64][260] f32 = 66560 B, stride 260 -> 2-way banks
  for (int half = 0; half < 2; ++half) {
    __syncthreads();  // all waves done with As/Bs (or previous round)
    if (wk == 1 && wm2 == half) {
#pragma unroll
      for (int mt = 0; mt < 4; ++mt)
#pragma unroll
        for (int nt = 0; nt < 8; ++nt) {
          int col = wn2 * 128 + nt * 16 + lm;
#pragma unroll
          for (int idx = 0; idx < 4; ++idx)
            red[(mt * 16 + quad * 4 + idx) * 260 + col] = acc[mt][nt][idx];
        }
    }
    __syncthreads();
    if (wk == 0 && wm2 == half) {
#pragma unroll
      for (int nt = 0; nt < 8; ++nt) {
        int col = wn2 * 128 + nt * 16 + lm;
        float bv = bias[col];
#pragma unroll
        for (int mt = 0; mt < 4; ++mt) {
          int rbase = m0 + half * 64 + mt * 16 + quad * 4;
#pragma unroll
          for (int idx = 0; idx < 4; ++idx)
            out[(size_t)(rbase + idx) * ODIM + col] =
                acc[mt][nt][idx] + red[(mt * 16 + quad * 4 + idx) * 260 + col] + bv;
        }
      }
    }
  }
}

extern "C" void kernel_launch(void* const* d_in, const int* in_sizes, int n_in,
                              void* d_out, int out_size, void* d_ws, size_t ws_size,
                              hipStream_t stream) {
  const float* x = (const float*)d_in[0];
  const float* fc = (const float*)d_in[1];
  const float* bias = (const float*)d_in[2];
  float* out = (float*)d_out;
  unsigned short* Wr = (unsigned short*)d_ws;  // 2 MB of workspace

  hipLaunchKernelGGL(wconv, dim3(1024), dim3(256), 0, stream, fc, Wr);
  hipLaunchKernelGGL(fkan_gemm, dim3(256), dim3(512), 0, stream, x, Wr, bias, out);
}

// Round 7
// 132.560 us; speedup vs baseline: 1.2521x; 1.0610x over previous
//
#include <hip/hip_runtime.h>

// NaiveFourierKANLayer: y = cos-features @ W0^T + sin-features @ W1^T + bias
// N=32768, INPUTDIM=64, OUTDIM=256, GRIDSIZE=32 -> GEMM M=32768, N=256, K=4096
//
// R9 changes vs R8 (83.2 us gemm, MfmaUtil 35, VALUBusy 25.4, conflicts 2.1M):
//  - B removed from LDS entirely. wconv now emits Wr FRAGMENT-MAJOR: for each
//    (kt, wk, wn2) an 8KB contiguous block = 8 fragments x (64 lanes x 16B)
//    in exact per-lane read order. fkan_gemm loads B as 8 fully-coalesced
//    1KB global_load_dwordx4 per wave per kt (L2-resident, ~15 TB/s demand
//    vs 34.5 ceiling), rolling-prefetched one kt ahead into registers
//    (breg[nt] reload issued right after its 4 consuming MFMAs).
//    LDS port busy drops ~1730 -> ~580 cyc/CU-kt (A only); the per-kt
//    barrier now only publishes A features.
//  - Per-lane B data is bit-identical to the old LDS image -> MFMA code,
//    A-path, split-k and epilogue unchanged (verified forms).
//  - LDS: As dbuf 32KB + separate 66.5KB f32 reduction scratch (no carving).

#define IDIM 64
#define ODIM 256
#define KDIM 4096
#define BM 128

typedef __attribute__((ext_vector_type(8))) unsigned short ushort8_t;
typedef __bf16 bf16x8 __attribute__((ext_vector_type(8)));
typedef float floatx4 __attribute__((ext_vector_type(4)));

__device__ __forceinline__ unsigned short f2bf_rne(float f) {
  unsigned int u = __float_as_uint(f);
  return (unsigned short)((u + 0x7FFFu + ((u >> 16) & 1u)) >> 16);
}

// ---- weight gather+convert: fc(2,256,64,32) fp32 -> Wr fragment-major bf16 ----
// Wr granule index t (16B each, 131072 total):
//   lane = t&63, j = (t>>6)&7, bb = t>>9;  bb = kt*4 + wk*2 + wn2
// holds W[o][k] for o = wn2*128 + j*16 + (lane&15),
//   k = kt*64 + (wk*4 + (lane>>4))*8 + e, e=0..7
// i.e. c = wk, g = (lane>>4)*8 + e, i = kt  (k = i*64 + c*32 + g)
__global__ void __launch_bounds__(256) wconv(const float* __restrict__ fc,
                                             unsigned short* __restrict__ Wr) {
  int t = blockIdx.x * 256 + threadIdx.x;  // granule index 0..131071
  int lane = t & 63;
  int j = (t >> 6) & 7;
  int bb = t >> 9;
  int wn2 = bb & 1;
  int wk = (bb >> 1) & 1;
  int kt = bb >> 2;
  int o = wn2 * 128 + j * 16 + (lane & 15);
  int g0 = (lane >> 4) * 8;
  const float* src = fc + ((size_t)wk << 19) + o * 2048 + kt * 32 + g0;
  const float4 v0 = *(const float4*)(src);
  const float4 v1 = *(const float4*)(src + 4);
  ushort8_t r;
  r[0] = f2bf_rne(v0.x);
  r[1] = f2bf_rne(v0.y);
  r[2] = f2bf_rne(v0.z);
  r[3] = f2bf_rne(v0.w);
  r[4] = f2bf_rne(v1.x);
  r[5] = f2bf_rne(v1.y);
  r[6] = f2bf_rne(v1.z);
  r[7] = f2bf_rne(v1.w);
  *(ushort8_t*)(Wr + (size_t)t * 8) = r;
}

// ---- fused feature-gen + GEMM ----
__global__ void __launch_bounds__(512, 2) fkan_gemm(const float* __restrict__ X,
                                                    const unsigned short* __restrict__ Wr,
                                                    const float* __restrict__ bias,
                                                    float* __restrict__ out) {
  __shared__ __align__(16) unsigned short As[2][8192];  // A dbuf, 32 KB
  __shared__ __align__(16) float red[64 * 260];         // split-k scratch, 66.5 KB

  const int t = threadIdx.x;
  const int wv = t >> 6;          // wave 0..7
  const int ln = t & 63;
  const int lm = ln & 15;
  const int quad = ln >> 4;
  const int wk = wv & 1;          // k-half (chunks wk*4 .. wk*4+3)
  const int wn2 = (wv >> 1) & 1;  // col-half (128 cols)
  const int wm2 = wv >> 2;        // row-half (64 rows)
  const int m0 = blockIdx.x * BM;

  // feature role: 4 threads per row, thread q owns g = 8q+1 .. 8q+8
  const int arow = t >> 2;  // 0..127
  const int q = t & 3;
  const float g0f = (float)(8 * q + 1);

  // A write granules (kt-invariant, XOR-swizzled) — verified R2/R3 formulas
  const int ga_c = arow * 8 + (q ^ (arow & 7));
  const int ga_s = arow * 8 + ((4 + q) ^ (arow & 7));

  // B fragment-major base for this wave's (wk, wn2): per kt an 8KB block
  const unsigned short* const bwave = Wr + (size_t)(wk * 2 + wn2) * 4096 + ln * 8;

  floatx4 acc[4][8];
#pragma unroll
  for (int a = 0; a < 4; ++a)
#pragma unroll
    for (int b = 0; b < 8; ++b)
      acc[a][b] = (floatx4){0.0f, 0.0f, 0.0f, 0.0f};

  const float* xptr = X + (size_t)(m0 + arow) * IDIM;

  // ---- A staging: chain-of-8 Fourier recurrence, one (cos,sin) granule pair
  auto features = [&](float xv, int buf) {
    const float inv2pi = 0.15915494309189535f;
    float u = xv * inv2pi;  // x in revolutions
    float u0 = u * g0f;     // g0*x in revolutions
    float c1 = __builtin_amdgcn_cosf(u);
    float s1 = __builtin_amdgcn_sinf(u);
    float C = __builtin_amdgcn_cosf(u0);
    float S = __builtin_amdgcn_sinf(u0);
    bf16x8 cb, sb;
    cb[0] = (__bf16)C;
    sb[0] = (__bf16)S;
#pragma unroll
    for (int jj = 1; jj < 8; ++jj) {
      float Cn = __builtin_fmaf(C, c1, -(S * s1));
      float Sn = __builtin_fmaf(S, c1, (C * s1));
      C = Cn;
      S = Sn;
      cb[jj] = (__bf16)C;
      sb[jj] = (__bf16)S;
    }
    ushort8_t* As8 = (ushort8_t*)As[buf];
    As8[ga_c] = __builtin_bit_cast(ushort8_t, cb);
    As8[ga_s] = __builtin_bit_cast(ushort8_t, sb);
  };

  bf16x8 breg[8];  // current kt's B fragments (register-resident)

  // ---- k-step: compute current kt from As[cur]+breg; rolling-prefetch
  //      breg <- kt `ktn`; features(x[ktn]) -> As[nxt]; barrier.
  auto ktstep = [&](int ktn, int cur, int nxt) {
    float xn = xptr[ktn];
    const ushort8_t* A8 = (const ushort8_t*)As[cur];
    const int ch = wk * 4 + quad;
    bf16x8 af[4];
#pragma unroll
    for (int mt = 0; mt < 4; ++mt) {
      int r = wm2 * 64 + mt * 16 + lm;
      af[mt] = __builtin_bit_cast(bf16x8, A8[r * 8 + (ch ^ (r & 7))]);
    }
    const unsigned short* bn = bwave + (size_t)ktn * 16384;  // 4 blocks of 4096

    __builtin_amdgcn_s_setprio(1);
#pragma unroll
    for (int nt = 0; nt < 8; ++nt) {
#pragma unroll
      for (int mt = 0; mt < 4; ++mt)
        acc[mt][nt] = __builtin_amdgcn_mfma_f32_16x16x32_bf16(
            af[mt], breg[nt], acc[mt][nt], 0, 0, 0);
      // reload breg[nt] for kt=ktn right after its last use (WAR-safe in-order)
      breg[nt] = __builtin_bit_cast(bf16x8, *(const ushort8_t*)(bn + nt * 512));
    }
    __builtin_amdgcn_s_setprio(0);

    features(xn, nxt);  // independent VALU/trans, overlaps load returns
    __syncthreads();
  };

  // ---- tail: compute last kt, no prefetch
  auto ktlast = [&](int cur) {
    const ushort8_t* A8 = (const ushort8_t*)As[cur];
    const int ch = wk * 4 + quad;
    bf16x8 af[4];
#pragma unroll
    for (int mt = 0; mt < 4; ++mt) {
      int r = wm2 * 64 + mt * 16 + lm;
      af[mt] = __builtin_bit_cast(bf16x8, A8[r * 8 + (ch ^ (r & 7))]);
    }
    __builtin_amdgcn_s_setprio(1);
#pragma unroll
    for (int nt = 0; nt < 8; ++nt)
#pragma unroll
      for (int mt = 0; mt < 4; ++mt)
        acc[mt][nt] = __builtin_amdgcn_mfma_f32_16x16x32_bf16(
            af[mt], breg[nt], acc[mt][nt], 0, 0, 0);
    __builtin_amdgcn_s_setprio(0);
  };

  // ---- prologue: breg <- kt 0; features(x0) -> buf 0
#pragma unroll
  for (int nt = 0; nt < 8; ++nt)
    breg[nt] = __builtin_bit_cast(bf16x8, *(const ushort8_t*)(bwave + nt * 512));
  features(xptr[0], 0);
  __syncthreads();

  // ---- steady state: unrolled x2 so dbuf index is compile-time
  for (int kt = 0; kt < 62; kt += 2) {
    ktstep(kt + 1, 0, 1);  // computes kt
    ktstep(kt + 2, 1, 0);  // computes kt+1
  }
  ktstep(63, 0, 1);  // computes kt=62
  ktlast(1);         // computes kt=63

  // ---- split-k reduction + store: wk=1 partials via padded LDS scratch ----
  for (int half = 0; half < 2; ++half) {
    __syncthreads();
    if (wk == 1 && wm2 == half) {
#pragma unroll
      for (int mt = 0; mt < 4; ++mt)
#pragma unroll
        for (int nt = 0; nt < 8; ++nt) {
          int col = wn2 * 128 + nt * 16 + lm;
#pragma unroll
          for (int idx = 0; idx < 4; ++idx)
            red[(mt * 16 + quad * 4 + idx) * 260 + col] = acc[mt][nt][idx];
        }
    }
    __syncthreads();
    if (wk == 0 && wm2 == half) {
#pragma unroll
      for (int nt = 0; nt < 8; ++nt) {
        int col = wn2 * 128 + nt * 16 + lm;
        float bv = bias[col];
#pragma unroll
        for (int mt = 0; mt < 4; ++mt) {
          int rbase = m0 + half * 64 + mt * 16 + quad * 4;
#pragma unroll
          for (int idx = 0; idx < 4; ++idx)
            out[(size_t)(rbase + idx) * ODIM + col] =
                acc[mt][nt][idx] + red[(mt * 16 + quad * 4 + idx) * 260 + col] + bv;
        }
      }
    }
  }
}

extern "C" void kernel_launch(void* const* d_in, const int* in_sizes, int n_in,
                              void* d_out, int out_size, void* d_ws, size_t ws_size,
                              hipStream_t stream) {
  const float* x = (const float*)d_in[0];
  const float* fc = (const float*)d_in[1];
  const float* bias = (const float*)d_in[2];
  float* out = (float*)d_out;
  unsigned short* Wr = (unsigned short*)d_ws;  // 2 MB of workspace

  hipLaunchKernelGGL(wconv, dim3(512), dim3(256), 0, stream, fc, Wr);
  hipLaunchKernelGGL(fkan_gemm, dim3(256), dim3(512), 0, stream, x, Wr, bias, out);
}